// Round 13
// baseline (330.356 us; speedup 1.0000x reference)
//
#include <hip/hip_runtime.h>
#include <math.h>

#define KNB 12
#define NCELLS 4096

// ---------------------------------------------------------------- helpers

__device__ __forceinline__ unsigned umin32(unsigned a, unsigned b) {
    unsigned r; asm("v_min_u32 %0, %1, %2" : "=v"(r) : "v"(a), "v"(b)); return r;
}
__device__ __forceinline__ unsigned umax32(unsigned a, unsigned b) {
    unsigned r; asm("v_max_u32 %0, %1, %2" : "=v"(r) : "v"(a), "v"(b)); return r;
}

__device__ __forceinline__ float fm(float a, float b) { return __fmul_rn(a, b); }
__device__ __forceinline__ float fa(float a, float b) { return __fadd_rn(a, b); }
__device__ __forceinline__ float fs(float a, float b) { return __fsub_rn(a, b); }
__device__ __forceinline__ float fsignf(float a, float b) { return (b >= 0.0f) ? fabsf(a) : -fabsf(a); }

__device__ float slapy2_(float x, float y) {
    float xa = fabsf(x), ya = fabsf(y);
    float w = fmaxf(xa, ya), z = fminf(xa, ya);
    if (z == 0.0f) return w;
    float q = z / w;
    return fm(w, __fsqrt_rn(fa(1.0f, fm(q, q))));
}

__device__ void slartg_(float f, float g, float& c, float& s, float& r) {
    if (g == 0.0f) { c = 1.0f; s = 0.0f; r = f; }
    else if (f == 0.0f) { c = 0.0f; s = (g >= 0.0f) ? 1.0f : -1.0f; r = fabsf(g); }
    else {
        float d = __fsqrt_rn(fa(fm(f, f), fm(g, g)));
        c = fabsf(f) / d;
        r = (f >= 0.0f) ? d : -d;
        s = g / r;
    }
}

__device__ void slaev2_(float a, float b, float cc,
                        float& rt1, float& rt2, float& cs1, float& sn1) {
    float sm = fa(a, cc), df = fs(a, cc), adf = fabsf(df);
    float tb = fa(b, b), ab = fabsf(tb);
    float acmx, acmn;
    if (fabsf(a) > fabsf(cc)) { acmx = a; acmn = cc; } else { acmx = cc; acmn = a; }
    float rt;
    if (adf > ab)      { float q = ab / adf; rt = fm(adf, __fsqrt_rn(fa(1.0f, fm(q, q)))); }
    else if (adf < ab) { float q = adf / ab; rt = fm(ab,  __fsqrt_rn(fa(1.0f, fm(q, q)))); }
    else               rt = fm(ab, __fsqrt_rn(2.0f));
    int sgn1;
    if (sm < 0.0f) {
        rt1 = fm(0.5f, fs(sm, rt)); sgn1 = -1;
        rt2 = fs(fm(acmx / rt1, acmn), fm(b / rt1, b));
    } else if (sm > 0.0f) {
        rt1 = fm(0.5f, fa(sm, rt)); sgn1 = 1;
        rt2 = fs(fm(acmx / rt1, acmn), fm(b / rt1, b));
    } else { rt1 = fm(0.5f, rt); rt2 = fm(-0.5f, rt); sgn1 = 1; }
    int sgn2; float cs;
    if (df >= 0.0f) { cs = fa(df, rt); sgn2 = 1; } else { cs = fs(df, rt); sgn2 = -1; }
    float acs = fabsf(cs);
    if (acs > ab) {
        float ct = -tb / cs;
        sn1 = 1.0f / __fsqrt_rn(fa(1.0f, fm(ct, ct)));
        cs1 = fm(ct, sn1);
    } else {
        if (ab == 0.0f) { cs1 = 1.0f; sn1 = 0.0f; }
        else {
            float tn = -cs / tb;
            cs1 = 1.0f / __fsqrt_rn(fa(1.0f, fm(tn, tn)));
            sn1 = fm(tn, cs1);
        }
    }
    if (sgn1 == sgn2) { float tn = cs1; cs1 = -sn1; sn1 = tn; }
}

#define Z(r, c)  wk[((r) - 1) * 3 + ((c) - 1)]
#define D(i)     wk[8 + (i)]
#define E(i)     wk[11 + (i)]
#define WC(i)    wk[13 + (i)]
#define WSN(i)   wk[15 + (i)]

__device__ __forceinline__ void rotcf(float* wk, int j1, int j2, float ct, float st) {
    for (int r = 1; r <= 3; ++r) {
        float temp = Z(r, j2);
        Z(r, j2) = fs(fm(ct, temp), fm(st, Z(r, j1)));
        Z(r, j1) = fa(fm(st, temp), fm(ct, Z(r, j1)));
    }
}

// Faithful f32 ssyevd path (ssytd2 'L' -> ssteqr 'I' -> sormtr), 3x3 lower.
__device__ void eig3_smallest_f32(float* wk,
                                  float a00, float a10, float a20,
                                  float a11, float a21, float a22,
                                  float& v1o, float& v2o, float& v3o) {
    for (int r = 1; r <= 3; ++r)
        for (int c = 1; c <= 3; ++c) Z(r, c) = (r == c) ? 1.0f : 0.0f;

    float tau = 0.0f, v3 = 0.0f;
    D(1) = a00;
    if (a20 != 0.0f) {
        float xn = fabsf(a20);
        float beta = -fsignf(slapy2_(a10, xn), a10);
        tau = fs(beta, a10) / beta;
        float rinv = 1.0f / fs(a10, beta);
        v3 = fm(a20, rinv);
        E(1) = beta;
        float w1 = fa(fm(tau, a11), fm(tau, fm(a21, v3)));
        float w2 = fa(fm(tau, a21), fm(fm(tau, v3), a22));
        float dot = fa(w1, fm(w2, v3));
        float al = fm(fm(-0.5f, tau), dot);
        w1 = fa(w1, al);
        w2 = fa(w2, fm(al, v3));
        D(2) = fs(fs(a11, w1), w1);
        E(2) = fs(fs(a21, fm(v3, w1)), w2);
        D(3) = fs(fs(a22, fm(v3, w2)), fm(w2, v3));
    } else {
        E(1) = a10; D(2) = a11; E(2) = a21; D(3) = a22;
    }

    const float eps = 5.9604645e-8f;
    const float eps2 = 3.5527137e-15f;
    const float safmin = 1.17549435e-38f;
    int jtot = 0; const int nmaxit = 90;
    int l1 = 1;
    while (l1 <= 3) {
        if (l1 > 1) E(l1 - 1) = 0.0f;
        int m;
        for (m = l1; m <= 2; ++m) {
            float tst = fabsf(E(m));
            if (tst == 0.0f) break;
            if (tst <= fm(fm(__fsqrt_rn(fabsf(D(m))), __fsqrt_rn(fabsf(D(m + 1)))), eps)) {
                E(m) = 0.0f; break;
            }
        }
        int l = l1, lend = m;
        l1 = m + 1;
        if (lend == l) continue;
        if (fabsf(D(lend)) < fabsf(D(l))) { int t = l; l = lend; lend = t; }
        if (lend > l) {
            for (;;) {
                int mq = lend;
                if (l != lend) {
                    for (mq = l; mq <= lend - 1; ++mq) {
                        float tst = fm(E(mq), E(mq));
                        if (tst <= fa(fm(fm(eps2, fabsf(D(mq))), fabsf(D(mq + 1))), safmin)) break;
                    }
                }
                if (mq < lend) E(mq) = 0.0f;
                float p = D(l);
                if (mq == l) { l += 1; if (l <= lend) continue; break; }
                if (mq == l + 1) {
                    float rt1, rt2, cc, ss;
                    slaev2_(D(l), E(l), D(l + 1), rt1, rt2, cc, ss);
                    rotcf(wk, l, l + 1, cc, ss);
                    D(l) = rt1; D(l + 1) = rt2; E(l) = 0.0f;
                    l += 2; if (l <= lend) continue; break;
                }
                if (jtot == nmaxit) break;
                jtot++;
                float g = fs(D(l + 1), p) / fm(2.0f, E(l));
                float r = slapy2_(g, 1.0f);
                g = fa(fs(D(mq), p), E(l) / fa(g, fsignf(r, g)));
                float s_ = 1.0f, c_ = 1.0f; p = 0.0f;
                for (int i = mq - 1; i >= l; --i) {
                    float f = fm(s_, E(i)), b = fm(c_, E(i));
                    slartg_(g, f, c_, s_, r);
                    if (i != mq - 1) E(i + 1) = r;
                    g = fs(D(i + 1), p);
                    r = fa(fm(fs(D(i), g), s_), fm(fm(2.0f, c_), b));
                    p = fm(s_, r);
                    D(i + 1) = fa(g, p);
                    g = fs(fm(c_, r), b);
                    WC(i) = c_; WSN(i) = -s_;
                }
                for (int i = mq - 1; i >= l; --i) rotcf(wk, i, i + 1, WC(i), WSN(i));
                D(l) = fs(D(l), p); E(l) = g;
            }
        } else {
            for (;;) {
                int mq = lend;
                if (l != lend) {
                    for (mq = l; mq >= lend + 1; --mq) {
                        float tst = fm(E(mq - 1), E(mq - 1));
                        if (tst <= fa(fm(fm(eps2, fabsf(D(mq))), fabsf(D(mq - 1))), safmin)) break;
                    }
                }
                if (mq > lend) E(mq - 1) = 0.0f;
                float p = D(l);
                if (mq == l) { l -= 1; if (l >= lend) continue; break; }
                if (mq == l - 1) {
                    float rt1, rt2, cc, ss;
                    slaev2_(D(l - 1), E(l - 1), D(l), rt1, rt2, cc, ss);
                    rotcf(wk, l - 1, l, cc, ss);
                    D(l - 1) = rt1; D(l) = rt2; E(l - 1) = 0.0f;
                    l -= 2; if (l >= lend) continue; break;
                }
                if (jtot == nmaxit) break;
                jtot++;
                float g = fs(D(l - 1), p) / fm(2.0f, E(l - 1));
                float r = slapy2_(g, 1.0f);
                g = fa(fs(D(mq), p), E(l - 1) / fa(g, fsignf(r, g)));
                float s_ = 1.0f, c_ = 1.0f; p = 0.0f;
                for (int i = mq; i <= l - 1; ++i) {
                    float f = fm(s_, E(i)), b = fm(c_, E(i));
                    slartg_(g, f, c_, s_, r);
                    if (i != mq) E(i - 1) = r;
                    g = fs(D(i), p);
                    r = fa(fm(fs(D(i + 1), g), s_), fm(fm(2.0f, c_), b));
                    p = fm(s_, r);
                    D(i) = fa(g, p);
                    g = fs(fm(c_, r), b);
                    WC(i) = c_; WSN(i) = s_;
                }
                for (int i = mq; i <= l - 1; ++i) rotcf(wk, i, i + 1, WC(i), WSN(i));
                D(l) = fs(D(l), p); E(l - 1) = g;
            }
        }
    }
    for (int ii = 2; ii <= 3; ++ii) {
        int i = ii - 1, kk = i; float p = D(i);
        for (int j = ii; j <= 3; ++j) if (D(j) < p) { kk = j; p = D(j); }
        if (kk != i) {
            D(kk) = D(i); D(i) = p;
            for (int r = 1; r <= 3; ++r) { float t = Z(r, i); Z(r, i) = Z(r, kk); Z(r, kk) = t; }
        }
    }
    if (tau != 0.0f) {
        for (int c = 1; c <= 3; ++c) {
            float ss = fa(Z(2, c), fm(v3, Z(3, c)));
            float t = fm(tau, ss);
            Z(2, c) = fs(Z(2, c), t);
            Z(3, c) = fs(Z(3, c), fm(t, v3));
        }
    }
    v1o = Z(1, 1); v2o = Z(2, 1); v3o = Z(3, 1);
}

__device__ void threefry2x32_(unsigned k0, unsigned k1, unsigned c0, unsigned c1,
                              unsigned& o0, unsigned& o1) {
    const unsigned rot[8] = {13u, 15u, 26u, 6u, 17u, 29u, 16u, 24u};
    unsigned ks[3] = {k0, k1, k0 ^ k1 ^ 0x1BD11BDAu};
    unsigned x0 = c0 + k0, x1 = c1 + k1;
    for (int blk = 0; blk < 5; ++blk) {
        const unsigned* r = &rot[(blk & 1) * 4];
        for (int i = 0; i < 4; ++i) {
            x0 += x1;
            x1 = (x1 << r[i]) | (x1 >> (32 - r[i]));
            x1 ^= x0;
        }
        x0 += ks[(blk + 1) % 3];
        x1 += ks[(blk + 2) % 3] + (unsigned)(blk + 1);
    }
    o0 = x0; o1 = x1;
}

__device__ float noise_diag_(int j) {
    unsigned m = (unsigned)(4 * j);
    unsigned o0, o1;
    threefry2x32_(0u, 42u, m, 150u + m, o0, o1);
    unsigned bits = (o0 >> 9) | 0x3f800000u;
    float u = fs(__uint_as_float(bits), 1.0f);
    return fm(fs(u, 0.5f), 1e-8f);
}

__device__ __forceinline__ float angf(float ax, float ay, float az,
                                      float bx, float by, float bz) {
    float cx = ay * bz - az * by;
    float cy = az * bx - ax * bz;
    float cz = ax * by - ay * bx;
    float cn = sqrtf(cx * cx + cy * cy + cz * cz);
    float d  = ax * bx + ay * by + az * bz;
    return atan2f(cn, d);
}

__device__ __forceinline__ int cellof(float x, float y, float z) {
    int cx = (int)(x * 16.0f); cx = (cx > 15) ? 15 : cx;
    int cy = (int)(y * 16.0f); cy = (cy > 15) ? 15 : cy;
    int cz = (int)(z * 16.0f); cz = (cz > 15) ? 15 : cz;
    return cx * 256 + cy * 16 + cz;
}

// ---------------------------------------------------------------- grid build

__global__ void k_zero(int* __restrict__ cellCnt) {
    int t = blockIdx.x * blockDim.x + threadIdx.x;
    if (t < NCELLS) cellCnt[t] = 0;
}

__global__ void k_prep(const float* __restrict__ pts, float4* __restrict__ pos4,
                       int* __restrict__ cellCnt, int n) {
    int i = blockIdx.x * blockDim.x + threadIdx.x;
    if (i < n) {
        float x = pts[i * 3], y = pts[i * 3 + 1], z = pts[i * 3 + 2];
        float sq = fa(fa(fm(x, x), fm(y, y)), fm(z, z));
        pos4[i] = make_float4(x, y, z, sq);
        atomicAdd(&cellCnt[cellof(x, y, z)], 1);
    }
}

__global__ __launch_bounds__(256) void k_scan(const int* __restrict__ cellCnt,
                                              int* __restrict__ cellStart,
                                              int* __restrict__ cellCur, int n) {
    __shared__ int part[256];
    int t = threadIdx.x;
    int s = 0;
    for (int z = 0; z < 16; ++z) s += cellCnt[t * 16 + z];
    part[t] = s;
    __syncthreads();
    for (int off = 1; off < 256; off <<= 1) {
        int v = (t >= off) ? part[t - off] : 0;
        __syncthreads();
        part[t] += v;
        __syncthreads();
    }
    int run = part[t] - s;
    for (int z = 0; z < 16; ++z) {
        int idx = t * 16 + z;
        cellStart[idx] = run;
        cellCur[idx] = run;
        run += cellCnt[idx];
    }
    if (t == 255) cellStart[NCELLS] = n;
}

__global__ void k_scatter(const float4* __restrict__ pos4, int* __restrict__ cellCur,
                          float4* __restrict__ spos4, int* __restrict__ sidx, int n) {
    int i = blockIdx.x * blockDim.x + threadIdx.x;
    if (i < n) {
        float4 p = pos4[i];
        int c = cellof(p.x, p.y, p.z);
        int pos = atomicAdd(&cellCur[c], 1);
        spos4[pos] = p;
        sidx[pos] = i;
    }
}

// ---------------------------------------------------------------- KNN (grid)
#define KEY_WORST 0xC0001FFFFFFFFFFFull
#define CAND 512

__device__ __forceinline__ void final_pops(unsigned long long* row, int cnt, int lane,
                                           double& mykey, unsigned long long& twelfth) {
    double k0 = __longlong_as_double((long long)KEY_WORST);
    if (lane < cnt) k0 = __longlong_as_double((long long)row[lane]);
    mykey = __longlong_as_double((long long)KEY_WORST);
    double last = mykey;
    for (int r = 0; r < KNB; ++r) {
        double mx = k0;
#pragma unroll
        for (int off = 32; off >= 1; off >>= 1)
            mx = fmax(mx, __shfl_xor(mx, off, 64));
        if (k0 == mx) k0 = __longlong_as_double((long long)KEY_WORST);
        if (lane == r) mykey = mx;
        last = mx;
    }
    twelfth = (unsigned long long)__double_as_longlong(last);
}

__global__ __launch_bounds__(256) void k_knn(const float4* __restrict__ pos4,
                                             const float4* __restrict__ spos4,
                                             const int* __restrict__ sidx,
                                             const int* __restrict__ cellStart,
                                             int* __restrict__ cols, int n) {
    __shared__ int scand[4][CAND];
    __shared__ unsigned long long scb[4][64];

    int lane = threadIdx.x & 63;
    int wv = threadIdx.x >> 6;
    int i = blockIdx.x * 4 + wv;
    if (i >= n) return;
    float4 P = pos4[i];

    int cix = (int)(P.x * 16.0f); cix = (cix > 15) ? 15 : cix;
    int ciy = (int)(P.y * 16.0f); ciy = (ciy > 15) ? 15 : ciy;
    int ciz = (int)(P.z * 16.0f); ciz = (ciz > 15) ? 15 : ciz;
    int zlo = (ciz - 2 > 0) ? (ciz - 2) : 0;
    int zhi = (ciz + 2 < 15) ? (ciz + 2) : 15;

    // lane t<25: (x,y) column range over z in [zlo, zhi]
    int len = 0, st = 0;
    if (lane < 25) {
        int dx = lane / 5 - 2, dy = lane % 5 - 2;
        int cx = cix + dx, cy = ciy + dy;
        if (cx >= 0 && cx <= 15 && cy >= 0 && cy <= 15) {
            int base = cx * 256 + cy * 16;
            st = cellStart[base + zlo];
            len = cellStart[base + zhi + 1] - st;
        }
    }
    int inc = len;
#pragma unroll
    for (int off = 1; off <= 16; off <<= 1) {
        int o = __shfl_up(inc, off, 64);
        if (lane >= off) inc += o;
    }
    int pref = inc - len;
    int total = __shfl(inc, 24, 64);
    bool ovf = (total > CAND);

    // expand candidate list into LDS once (kills the per-candidate search)
    if (!ovf && lane < 25) {
        for (int e = 0; e < len; ++e) scand[wv][pref + e] = st + e;
    }
    __builtin_amdgcn_wave_barrier();

    // guard: nearest uncovered block face (domain-clipped faces -> +inf)
    const float cw = 1.0f / 16.0f;
    int lx = (cix - 2 > 0) ? (cix - 2) : 0, hx = (cix + 2 < 15) ? (cix + 2) : 15;
    int ly = (ciy - 2 > 0) ? (ciy - 2) : 0, hy = (ciy + 2 < 15) ? (ciy + 2) : 15;
    float g1 = (lx == 0)  ? 1e9f : (P.x - lx * cw);
    float g2 = (hx == 15) ? 1e9f : ((hx + 1) * cw - P.x);
    float g3 = (ly == 0)  ? 1e9f : (P.y - ly * cw);
    float g4 = (hy == 15) ? 1e9f : ((hy + 1) * cw - P.y);
    float g5 = (zlo == 0) ? 1e9f : (P.z - zlo * cw);
    float g6 = (zhi == 15)? 1e9f : ((zhi + 1) * cw - P.z);
    float guard = fminf(fminf(fminf(g1, g2), fminf(g3, g4)), fminf(g5, g6));
    float guard2 = guard * guard;

    // ---- pass 1: per-lane top-2 raw-bit d2
    unsigned b0 = 0xFFFFFFFFu, b1 = 0xFFFFFFFFu;
    if (!ovf) {
        for (int t = lane; t < total; t += 64) {
            int s = scand[wv][t];
            float4 Q = spos4[s];
            int j = sidx[s];
            float g = fm(P.x, Q.x);
            g = fmaf(P.y, Q.y, g);
            g = fmaf(P.z, Q.z, g);
            float d2 = fs(fa(P.w, Q.w), fm(2.0f, g));
            unsigned u = __float_as_uint(d2);
            if (j == i) u = 0xFFFFFFFFu;
            unsigned lo = umin32(b0, u);
            unsigned hi = umax32(b0, u);
            b0 = lo;
            b1 = umin32(b1, hi);
        }
    }

    // ---- T = 12th smallest captured (self excluded)
    unsigned T = 0xFFFFFFFFu;
    for (int r = 0; r < KNB; ++r) {
        unsigned mn = b0;
#pragma unroll
        for (int off = 32; off >= 1; off >>= 1) {
            unsigned o = (unsigned)__shfl_xor((int)mn, off, 64);
            mn = umin32(mn, o);
        }
        unsigned long long bl = __ballot(b0 == mn);
        int first = __ffsll(bl) - 1;
        if (lane == first) { b0 = b1; b1 = 0xFFFFFFFFu; }
        T = mn;
    }

    // ---- pass 2: collect {bits <= T, j != i}
    int cnt = 0;
    if (!ovf) {
        for (int t = lane; t < total; t += 64) {
            int s = scand[wv][t];
            float4 Q = spos4[s];
            int j = sidx[s];
            float g = fm(P.x, Q.x);
            g = fmaf(P.y, Q.y, g);
            g = fmaf(P.z, Q.z, g);
            float d2 = fs(fa(P.w, Q.w), fm(2.0f, g));
            unsigned u = __float_as_uint(d2);
            bool c = (u <= T) && (j != i);
            unsigned long long bl = __ballot(c);
            if (c) {
                int pos = cnt + (int)__popcll(bl & ((1ull << lane) - 1ull));
                unsigned us = u ^ (unsigned)(((int)u >> 31) | 0x80000000);
                unsigned long long kb = (((unsigned long long)us << 13) | (unsigned)j)
                                        | 0xC000000000000000ull;
                if (pos < 64) scb[wv][pos] = kb;
            }
            cnt += (int)__popcll(bl);
        }
    }

    bool fb = ovf || (cnt > 64) || (total < KNB + 1);
    double mykey; unsigned long long twelfth;
    if (!fb) {
        final_pops(scb[wv], cnt, lane, mykey, twelfth);
        unsigned u12 = (unsigned)((twelfth >> 13) & 0xFFFFFFFFull);
        unsigned ob12 = (u12 & 0x80000000u) ? (u12 ^ 0x80000000u) : ~u12;
        float d2_12 = __uint_as_float(ob12);
        if (!(d2_12 < guard2)) fb = true;
    }

    if (fb) {
        // solo full-scan exact fallback
        unsigned lst[KNB];
#pragma unroll
        for (int k = 0; k < KNB; ++k) lst[k] = 0xFFFFFFFFu;
        for (int j = lane; j < n; j += 64) {
            float4 Q = pos4[j];
            float g = fm(P.x, Q.x);
            g = fmaf(P.y, Q.y, g);
            g = fmaf(P.z, Q.z, g);
            float d2 = fs(fa(P.w, Q.w), fm(2.0f, g));
            unsigned u = __float_as_uint(d2);
            unsigned us = u ^ (unsigned)(((int)u >> 31) | 0x80000000);
            if (j == i) us = 0xFFFFFFFFu;
#pragma unroll
            for (int k = 0; k < KNB; ++k) {
                unsigned lo = umin32(lst[k], us);
                unsigned hi = umax32(lst[k], us);
                lst[k] = lo; us = hi;
            }
        }
        unsigned Ts = 0xFFFFFFFFu;
        for (int r = 0; r < KNB; ++r) {
            unsigned mn = lst[0];
#pragma unroll
            for (int off = 32; off >= 1; off >>= 1) {
                unsigned o = (unsigned)__shfl_xor((int)mn, off, 64);
                mn = umin32(mn, o);
            }
            unsigned long long bl = __ballot(lst[0] == mn);
            int first = __ffsll(bl) - 1;
            if (lane == first) {
#pragma unroll
                for (int k = 0; k < KNB - 1; ++k) lst[k] = lst[k + 1];
                lst[KNB - 1] = 0xFFFFFFFFu;
            }
            Ts = mn;
        }
        cnt = 0;
        for (int j = lane; j < n; j += 64) {
            float4 Q = pos4[j];
            float g = fm(P.x, Q.x);
            g = fmaf(P.y, Q.y, g);
            g = fmaf(P.z, Q.z, g);
            float d2 = fs(fa(P.w, Q.w), fm(2.0f, g));
            unsigned u = __float_as_uint(d2);
            unsigned us = u ^ (unsigned)(((int)u >> 31) | 0x80000000);
            bool c = (us <= Ts) && (j != i);
            unsigned long long bl = __ballot(c);
            if (c) {
                int pos = cnt + (int)__popcll(bl & ((1ull << lane) - 1ull));
                unsigned long long kb = (((unsigned long long)us << 13) | (unsigned)j)
                                        | 0xC000000000000000ull;
                if (pos < 64) scb[wv][pos] = kb;
            }
            cnt += (int)__popcll(bl);
        }
        if (cnt > 64) cnt = 64;
        final_pops(scb[wv], cnt, lane, mykey, twelfth);
    }

    if (lane < KNB) {
        unsigned long long bits = (unsigned long long)__double_as_longlong(mykey);
        unsigned j = (unsigned)(bits & 0x1FFFu);
        unsigned u = (unsigned)((bits >> 13) & 0xFFFFFFFFull);
        unsigned ob = (u & 0x80000000u) ? (u ^ 0x80000000u) : ~u;
        float d2 = __uint_as_float(ob);
        cols[i * KNB + lane] = (d2 <= 0.25f) ? (int)j : i;
    }
}

// ---------------------------------------------------------------- normals
__global__ __launch_bounds__(64) void k_normals(const float4* __restrict__ pos4,
                                                const int* __restrict__ cols,
                                                float4* __restrict__ nrm4,
                                                float* __restrict__ out, int n) {
    __shared__ float swk[64][19];
    int i = blockIdx.x * blockDim.x + threadIdx.x;
    if (i >= n) return;
    float* wk = swk[threadIdx.x];

    float qx[KNB], qy[KNB], qz[KNB];
#pragma unroll
    for (int k = 0; k < KNB; ++k) {
        float4 q = pos4[cols[i * KNB + k]];
        qx[k] = q.x; qy[k] = q.y; qz[k] = q.z;
    }
    float sx = qx[0], sy = qy[0], sz = qz[0];
#pragma unroll
    for (int k = 1; k < KNB; ++k) { sx = fa(sx, qx[k]); sy = fa(sy, qy[k]); sz = fa(sz, qz[k]); }
    float mx = sx / 12.0f, my = sy / 12.0f, mz = sz / 12.0f;
    float c00 = 0, c10 = 0, c20 = 0, c11 = 0, c21 = 0, c22 = 0;
#pragma unroll
    for (int k = 0; k < KNB; ++k) {
        float dx = fs(qx[k], mx), dy = fs(qy[k], my), dz = fs(qz[k], mz);
        c00 = fa(c00, fm(dx, dx));
        c10 = fa(c10, fm(dy, dx));
        c20 = fa(c20, fm(dz, dx));
        c11 = fa(c11, fm(dy, dy));
        c21 = fa(c21, fm(dz, dy));
        c22 = fa(c22, fm(dz, dz));
    }
    c00 = c00 / 12.0f; c10 = c10 / 12.0f; c20 = c20 / 12.0f;
    c11 = c11 / 12.0f; c21 = c21 / 12.0f; c22 = c22 / 12.0f;
    float v0 = noise_diag_(0), v1 = noise_diag_(1), v2 = noise_diag_(2);
    float a00 = fa(c00, v0), a10 = fa(c10, v0), a20 = fa(c20, v0);
    float a11 = fa(c11, v1), a21 = fa(c21, v1), a22 = fa(c22, v2);
    float e1, e2, e3;
    eig3_smallest_f32(wk, a00, a10, a20, a11, a21, a22, e1, e2, e3);
    nrm4[i] = make_float4(e1, e2, e3, 0.0f);
    out[i]         = e1;
    out[n + i]     = e2;
    out[2 * n + i] = e3;
}

// ---------------------------------------------------------------- MLP chain
// One WAVE per point (8192 waves vs R12's 1536): l-MLPs split across each
// edge's 4-lane quad (8 of 32 hidden units per lane + quad shuffle-reduce);
// g-MLPs across 32 lanes (one hidden unit each + wave shuffle-reduce).
// Partial-sum reorder shifts outputs by ~1e-6 (tolerance 2e-2). Softmax
// serial order preserved bit-exact. sx padded (stride 17): R12 showed 1M
// LDS bank conflicts at stride 16.

struct WPtrs { const float* p[28]; };

// quad-split partial MLP: this lane handles h = q, q+4, ...
template <int NI, int NH, int NO>
__device__ __forceinline__ void mlp_quad(const float* __restrict__ w1,
                                         const float* __restrict__ b1,
                                         const float* __restrict__ w2,
                                         const float* in, int q, float* po) {
#pragma unroll
    for (int o = 0; o < NO; ++o) po[o] = 0.0f;
    for (int h = q; h < NH; h += 4) {
        float hh = b1[h];
#pragma unroll
        for (int ii = 0; ii < NI; ++ii) hh = fmaf(in[ii], w1[ii * NH + h], hh);
        hh = fmaxf(hh, 0.0f);
#pragma unroll
        for (int o = 0; o < NO; ++o) po[o] = fmaf(hh, w2[h * NO + o], po[o]);
    }
}

__global__ __launch_bounds__(256) void k_mlp(const float4* __restrict__ pos4,
                                             const int* __restrict__ cols,
                                             const float4* __restrict__ nrm4,
                                             WPtrs wp, float* __restrict__ out, int n) {
    __shared__ float sxm[4][12][17];
    __shared__ float sin_[4][20];
    __shared__ float slog[4][12];

    int lane = threadIdx.x & 63;
    int wv = threadIdx.x >> 6;
    int nn = blockIdx.x * 4 + wv;
    bool wact = (nn < n);
    int nnc = wact ? nn : (n - 1);
    int q = lane & 3;
    int k = lane >> 2;              // 0..15
    bool eact = wact && (k < 12);
    int kc = (k < 12) ? k : 11;

    // ---- stage A: edge features + l1 (quad-split)
    int col = cols[nnc * 12 + kc];
    float4 P = pos4[nnc], Q = pos4[col];
    float cx = Q.x - P.x, cy = Q.y - P.y, cz = Q.z - P.z;
    float dist = sqrtf(cx * cx + cy * cy + cz * cz);
    float4 NR = nrm4[nnc], NC = nrm4[col];
    float nrx = NR.x, nry = NR.y, nrz = NR.z;
    float a1 = angf(nrx, nry, nrz, cx, cy, cz);
    float a2 = angf(NC.x, NC.y, NC.z, cx, cy, cz);
    float a3 = angf(nrx, nry, nrz, NC.x, NC.y, NC.z);
    float in7[7] = {cx, cy, cz, dist, a1, a2, a3};

    float xr[16], po[16];
    mlp_quad<7, 32, 16>(wp.p[0], wp.p[1], wp.p[2], in7, q, po);
#pragma unroll
    for (int o = 0; o < 16; ++o) {
        po[o] += __shfl_xor(po[o], 1, 64);
        po[o] += __shfl_xor(po[o], 2, 64);
        xr[o] = wp.p[3][o] + po[o];
    }
    if (eact && q == 0) {
#pragma unroll
        for (int o = 0; o < 16; ++o) sxm[wv][k][o] = xr[o];
    }
    __syncthreads();

    // ---- g1 input: means + normal
    if (wact && lane < 16) {
        float s = 0;
        for (int kk = 0; kk < 12; ++kk) s += sxm[wv][kk][lane];
        sin_[wv][lane] = s / 12.0f;
    }
    if (wact && lane == 0) { sin_[wv][16] = nrx; sin_[wv][17] = nry; sin_[wv][18] = nrz; }
    __syncthreads();

    // ---- g1 (lane-split over 32 hidden)
    float g1o[8];
    {
        float in19[19];
#pragma unroll
        for (int ii = 0; ii < 19; ++ii) in19[ii] = sin_[wv][ii];
        float pg[8];
#pragma unroll
        for (int o = 0; o < 8; ++o) pg[o] = 0.0f;
        if (lane < 32) {
            float hh = wp.p[5][lane];
#pragma unroll
            for (int ii = 0; ii < 19; ++ii) hh = fmaf(in19[ii], wp.p[4][ii * 32 + lane], hh);
            hh = fmaxf(hh, 0.0f);
#pragma unroll
            for (int o = 0; o < 8; ++o) pg[o] = hh * wp.p[6][lane * 8 + o];
        }
#pragma unroll
        for (int o = 0; o < 8; ++o) {
#pragma unroll
            for (int m = 1; m <= 32; m <<= 1) pg[o] += __shfl_xor(pg[o], m, 64);
            g1o[o] = wp.p[7][o] + pg[o];
        }
    }

    // ---- l2 (quad-split)
    {
        float in24[24];
#pragma unroll
        for (int o = 0; o < 16; ++o) in24[o] = xr[o];
#pragma unroll
        for (int o = 0; o < 8; ++o) in24[16 + o] = g1o[o];
        mlp_quad<24, 32, 16>(wp.p[8], wp.p[9], wp.p[10], in24, q, po);
#pragma unroll
        for (int o = 0; o < 16; ++o) {
            po[o] += __shfl_xor(po[o], 1, 64);
            po[o] += __shfl_xor(po[o], 2, 64);
            xr[o] = wp.p[11][o] + po[o];
        }
    }
    if (eact && q == 0) {
#pragma unroll
        for (int o = 0; o < 16; ++o) sxm[wv][k][o] = xr[o];
    }
    __syncthreads();

    if (wact && lane < 16) {
        float s = 0;
        for (int kk = 0; kk < 12; ++kk) s += sxm[wv][kk][lane];
        sin_[wv][lane] = s / 12.0f;
    }
    __syncthreads();

    // ---- g2
    float g2o[8];
    {
        float in16[16];
#pragma unroll
        for (int ii = 0; ii < 16; ++ii) in16[ii] = sin_[wv][ii];
        float pg[8];
#pragma unroll
        for (int o = 0; o < 8; ++o) pg[o] = 0.0f;
        if (lane < 32) {
            float hh = wp.p[13][lane];
#pragma unroll
            for (int ii = 0; ii < 16; ++ii) hh = fmaf(in16[ii], wp.p[12][ii * 32 + lane], hh);
            hh = fmaxf(hh, 0.0f);
#pragma unroll
            for (int o = 0; o < 8; ++o) pg[o] = hh * wp.p[14][lane * 8 + o];
        }
#pragma unroll
        for (int o = 0; o < 8; ++o) {
#pragma unroll
            for (int m = 1; m <= 32; m <<= 1) pg[o] += __shfl_xor(pg[o], m, 64);
            g2o[o] = wp.p[15][o] + pg[o];
        }
    }

    // ---- l3 (quad-split)
    {
        float in24[24];
#pragma unroll
        for (int o = 0; o < 16; ++o) in24[o] = xr[o];
#pragma unroll
        for (int o = 0; o < 8; ++o) in24[16 + o] = g2o[o];
        mlp_quad<24, 32, 16>(wp.p[16], wp.p[17], wp.p[18], in24, q, po);
#pragma unroll
        for (int o = 0; o < 16; ++o) {
            po[o] += __shfl_xor(po[o], 1, 64);
            po[o] += __shfl_xor(po[o], 2, 64);
            xr[o] = wp.p[19][o] + po[o];
        }
    }
    if (eact && q == 0) {
#pragma unroll
        for (int o = 0; o < 16; ++o) sxm[wv][k][o] = xr[o];
    }
    __syncthreads();

    if (wact && lane < 16) {
        float s = 0;
        for (int kk = 0; kk < 12; ++kk) s += sxm[wv][kk][lane];
        sin_[wv][lane] = s / 12.0f;
    }
    __syncthreads();

    // ---- g3 (NO=12) + quat -> mat, feat (all lanes)
    float mat[9], feat[8];
    {
        float in16[16];
#pragma unroll
        for (int ii = 0; ii < 16; ++ii) in16[ii] = sin_[wv][ii];
        float pg[12];
#pragma unroll
        for (int o = 0; o < 12; ++o) pg[o] = 0.0f;
        if (lane < 32) {
            float hh = wp.p[21][lane];
#pragma unroll
            for (int ii = 0; ii < 16; ++ii) hh = fmaf(in16[ii], wp.p[20][ii * 32 + lane], hh);
            hh = fmaxf(hh, 0.0f);
#pragma unroll
            for (int o = 0; o < 12; ++o) pg[o] = hh * wp.p[22][lane * 12 + o];
        }
        float og[12];
#pragma unroll
        for (int o = 0; o < 12; ++o) {
#pragma unroll
            for (int m = 1; m <= 32; m <<= 1) pg[o] += __shfl_xor(pg[o], m, 64);
            og[o] = wp.p[23][o] + pg[o];
        }
        float q0 = og[0], q1 = og[1], q2 = og[2], q3 = og[3];
        float qn = sqrtf(q0 * q0 + q1 * q1 + q2 * q2 + q3 * q3) + 1e-8f;
        q0 /= qn; q1 /= qn; q2 /= qn; q3 /= qn;
        float qw = q0, qx = q1, qy = q2, qz = q3;
        mat[0] = 1.0f - 2.0f * (qy * qy + qz * qz);
        mat[1] = 2.0f * (qx * qy - qz * qw);
        mat[2] = 2.0f * (qx * qz + qy * qw);
        mat[3] = 2.0f * (qx * qy + qz * qw);
        mat[4] = 1.0f - 2.0f * (qx * qx + qz * qz);
        mat[5] = 2.0f * (qy * qz - qx * qw);
        mat[6] = 2.0f * (qx * qz - qy * qw);
        mat[7] = 2.0f * (qy * qz + qx * qw);
        mat[8] = 1.0f - 2.0f * (qx * qx + qy * qy);
#pragma unroll
        for (int o = 0; o < 8; ++o) feat[o] = og[4 + o];
    }

    // ---- l4 logits (quad-split over 64 hidden, NO=1)
    {
        float r0 = mat[0] * cx + mat[1] * cy + mat[2] * cz;
        float r1 = mat[3] * cx + mat[4] * cy + mat[5] * cz;
        float r2 = mat[6] * cx + mat[7] * cy + mat[8] * cz;
        float in27[27];
#pragma unroll
        for (int o = 0; o < 16; ++o) in27[o] = xr[o];
#pragma unroll
        for (int o = 0; o < 8; ++o) in27[16 + o] = feat[o];
        in27[24] = r0; in27[25] = r1; in27[26] = r2;
        float p0[1];
        mlp_quad<27, 64, 1>(wp.p[24], wp.p[25], wp.p[26], in27, q, p0);
        p0[0] += __shfl_xor(p0[0], 1, 64);
        p0[0] += __shfl_xor(p0[0], 2, 64);
        float logit = wp.p[27][0] + p0[0];
        if (eact && q == 0) slog[wv][k] = logit;
    }
    __syncthreads();

    // ---- softmax over 12 edges (serial order preserved)
    if (eact && q == 0) {
        float mx = slog[wv][0];
        for (int kk = 1; kk < 12; ++kk) mx = fmaxf(mx, slog[wv][kk]);
        float se = 0;
        for (int kk = 0; kk < 12; ++kk) se += expf(slog[wv][kk] - mx);
        float v = expf(slog[wv][k] - mx) / se;
        out[3 * n + k * n + nn] = v;
    }
}

// ---------------------------------------------------------------- launch

extern "C" void kernel_launch(void* const* d_in, const int* in_sizes, int n_in,
                              void* d_out, int out_size, void* d_ws, size_t ws_size,
                              hipStream_t stream) {
    const float* pts = (const float*)d_in[0];
    int n = in_sizes[0] / 3;

    char* w = (char*)d_ws;
    float4* pos4      = (float4*)w;                    w += (size_t)n * 16;
    int*    cols      = (int*)w;                       w += (size_t)n * KNB * 4;
    float4* nrm4      = (float4*)w;                    w += (size_t)n * 16;
    float4* spos4     = (float4*)w;                    w += (size_t)n * 16;
    int*    sidx      = (int*)w;                       w += (size_t)n * 4;
    int*    cellCnt   = (int*)w;                       w += (size_t)NCELLS * 4;
    int*    cellStart = (int*)w;                       w += (size_t)(NCELLS + 1) * 4;
    int*    cellCur   = (int*)w;
    float*  out       = (float*)d_out;

    WPtrs wp;
    for (int a = 0; a < 28; ++a) wp.p[a] = (const float*)d_in[a + 1];

    k_zero<<<(NCELLS + 255) / 256, 256, 0, stream>>>(cellCnt);
    k_prep<<<(n + 255) / 256, 256, 0, stream>>>(pts, pos4, cellCnt, n);
    k_scan<<<1, 256, 0, stream>>>(cellCnt, cellStart, cellCur, n);
    k_scatter<<<(n + 255) / 256, 256, 0, stream>>>(pos4, cellCur, spos4, sidx, n);
    k_knn<<<(n + 3) / 4, 256, 0, stream>>>(pos4, spos4, sidx, cellStart, cols, n);
    k_normals<<<(n + 63) / 64, 64, 0, stream>>>(pos4, cols, nrm4, out, n);
    k_mlp<<<(n + 3) / 4, 256, 0, stream>>>(pos4, cols, nrm4, wp, out, n);
}

// Round 14
// 290.965 us; speedup vs baseline: 1.1354x; 1.1354x over previous
//
#include <hip/hip_runtime.h>
#include <math.h>

#define KNB 12
#define NCELLS 4096

// ---------------------------------------------------------------- helpers

__device__ __forceinline__ unsigned umin32(unsigned a, unsigned b) {
    unsigned r; asm("v_min_u32 %0, %1, %2" : "=v"(r) : "v"(a), "v"(b)); return r;
}
__device__ __forceinline__ unsigned umax32(unsigned a, unsigned b) {
    unsigned r; asm("v_max_u32 %0, %1, %2" : "=v"(r) : "v"(a), "v"(b)); return r;
}

__device__ __forceinline__ float fm(float a, float b) { return __fmul_rn(a, b); }
__device__ __forceinline__ float fa(float a, float b) { return __fadd_rn(a, b); }
__device__ __forceinline__ float fs(float a, float b) { return __fsub_rn(a, b); }
__device__ __forceinline__ float fsignf(float a, float b) { return (b >= 0.0f) ? fabsf(a) : -fabsf(a); }

__device__ float slapy2_(float x, float y) {
    float xa = fabsf(x), ya = fabsf(y);
    float w = fmaxf(xa, ya), z = fminf(xa, ya);
    if (z == 0.0f) return w;
    float q = z / w;
    return fm(w, __fsqrt_rn(fa(1.0f, fm(q, q))));
}

__device__ void slartg_(float f, float g, float& c, float& s, float& r) {
    if (g == 0.0f) { c = 1.0f; s = 0.0f; r = f; }
    else if (f == 0.0f) { c = 0.0f; s = (g >= 0.0f) ? 1.0f : -1.0f; r = fabsf(g); }
    else {
        float d = __fsqrt_rn(fa(fm(f, f), fm(g, g)));
        c = fabsf(f) / d;
        r = (f >= 0.0f) ? d : -d;
        s = g / r;
    }
}

__device__ void slaev2_(float a, float b, float cc,
                        float& rt1, float& rt2, float& cs1, float& sn1) {
    float sm = fa(a, cc), df = fs(a, cc), adf = fabsf(df);
    float tb = fa(b, b), ab = fabsf(tb);
    float acmx, acmn;
    if (fabsf(a) > fabsf(cc)) { acmx = a; acmn = cc; } else { acmx = cc; acmn = a; }
    float rt;
    if (adf > ab)      { float q = ab / adf; rt = fm(adf, __fsqrt_rn(fa(1.0f, fm(q, q)))); }
    else if (adf < ab) { float q = adf / ab; rt = fm(ab,  __fsqrt_rn(fa(1.0f, fm(q, q)))); }
    else               rt = fm(ab, __fsqrt_rn(2.0f));
    int sgn1;
    if (sm < 0.0f) {
        rt1 = fm(0.5f, fs(sm, rt)); sgn1 = -1;
        rt2 = fs(fm(acmx / rt1, acmn), fm(b / rt1, b));
    } else if (sm > 0.0f) {
        rt1 = fm(0.5f, fa(sm, rt)); sgn1 = 1;
        rt2 = fs(fm(acmx / rt1, acmn), fm(b / rt1, b));
    } else { rt1 = fm(0.5f, rt); rt2 = fm(-0.5f, rt); sgn1 = 1; }
    int sgn2; float cs;
    if (df >= 0.0f) { cs = fa(df, rt); sgn2 = 1; } else { cs = fs(df, rt); sgn2 = -1; }
    float acs = fabsf(cs);
    if (acs > ab) {
        float ct = -tb / cs;
        sn1 = 1.0f / __fsqrt_rn(fa(1.0f, fm(ct, ct)));
        cs1 = fm(ct, sn1);
    } else {
        if (ab == 0.0f) { cs1 = 1.0f; sn1 = 0.0f; }
        else {
            float tn = -cs / tb;
            cs1 = 1.0f / __fsqrt_rn(fa(1.0f, fm(tn, tn)));
            sn1 = fm(tn, cs1);
        }
    }
    if (sgn1 == sgn2) { float tn = cs1; cs1 = -sn1; sn1 = tn; }
}

#define Z(r, c)  wk[((r) - 1) * 3 + ((c) - 1)]
#define D(i)     wk[8 + (i)]
#define E(i)     wk[11 + (i)]
#define WC(i)    wk[13 + (i)]
#define WSN(i)   wk[15 + (i)]

__device__ __forceinline__ void rotcf(float* wk, int j1, int j2, float ct, float st) {
    for (int r = 1; r <= 3; ++r) {
        float temp = Z(r, j2);
        Z(r, j2) = fs(fm(ct, temp), fm(st, Z(r, j1)));
        Z(r, j1) = fa(fm(st, temp), fm(ct, Z(r, j1)));
    }
}

// Faithful f32 ssyevd path (ssytd2 'L' -> ssteqr 'I' -> sormtr), 3x3 lower.
__device__ void eig3_smallest_f32(float* wk,
                                  float a00, float a10, float a20,
                                  float a11, float a21, float a22,
                                  float& v1o, float& v2o, float& v3o) {
    for (int r = 1; r <= 3; ++r)
        for (int c = 1; c <= 3; ++c) Z(r, c) = (r == c) ? 1.0f : 0.0f;

    float tau = 0.0f, v3 = 0.0f;
    D(1) = a00;
    if (a20 != 0.0f) {
        float xn = fabsf(a20);
        float beta = -fsignf(slapy2_(a10, xn), a10);
        tau = fs(beta, a10) / beta;
        float rinv = 1.0f / fs(a10, beta);
        v3 = fm(a20, rinv);
        E(1) = beta;
        float w1 = fa(fm(tau, a11), fm(tau, fm(a21, v3)));
        float w2 = fa(fm(tau, a21), fm(fm(tau, v3), a22));
        float dot = fa(w1, fm(w2, v3));
        float al = fm(fm(-0.5f, tau), dot);
        w1 = fa(w1, al);
        w2 = fa(w2, fm(al, v3));
        D(2) = fs(fs(a11, w1), w1);
        E(2) = fs(fs(a21, fm(v3, w1)), w2);
        D(3) = fs(fs(a22, fm(v3, w2)), fm(w2, v3));
    } else {
        E(1) = a10; D(2) = a11; E(2) = a21; D(3) = a22;
    }

    const float eps = 5.9604645e-8f;
    const float eps2 = 3.5527137e-15f;
    const float safmin = 1.17549435e-38f;
    int jtot = 0; const int nmaxit = 90;
    int l1 = 1;
    while (l1 <= 3) {
        if (l1 > 1) E(l1 - 1) = 0.0f;
        int m;
        for (m = l1; m <= 2; ++m) {
            float tst = fabsf(E(m));
            if (tst == 0.0f) break;
            if (tst <= fm(fm(__fsqrt_rn(fabsf(D(m))), __fsqrt_rn(fabsf(D(m + 1)))), eps)) {
                E(m) = 0.0f; break;
            }
        }
        int l = l1, lend = m;
        l1 = m + 1;
        if (lend == l) continue;
        if (fabsf(D(lend)) < fabsf(D(l))) { int t = l; l = lend; lend = t; }
        if (lend > l) {
            for (;;) {
                int mq = lend;
                if (l != lend) {
                    for (mq = l; mq <= lend - 1; ++mq) {
                        float tst = fm(E(mq), E(mq));
                        if (tst <= fa(fm(fm(eps2, fabsf(D(mq))), fabsf(D(mq + 1))), safmin)) break;
                    }
                }
                if (mq < lend) E(mq) = 0.0f;
                float p = D(l);
                if (mq == l) { l += 1; if (l <= lend) continue; break; }
                if (mq == l + 1) {
                    float rt1, rt2, cc, ss;
                    slaev2_(D(l), E(l), D(l + 1), rt1, rt2, cc, ss);
                    rotcf(wk, l, l + 1, cc, ss);
                    D(l) = rt1; D(l + 1) = rt2; E(l) = 0.0f;
                    l += 2; if (l <= lend) continue; break;
                }
                if (jtot == nmaxit) break;
                jtot++;
                float g = fs(D(l + 1), p) / fm(2.0f, E(l));
                float r = slapy2_(g, 1.0f);
                g = fa(fs(D(mq), p), E(l) / fa(g, fsignf(r, g)));
                float s_ = 1.0f, c_ = 1.0f; p = 0.0f;
                for (int i = mq - 1; i >= l; --i) {
                    float f = fm(s_, E(i)), b = fm(c_, E(i));
                    slartg_(g, f, c_, s_, r);
                    if (i != mq - 1) E(i + 1) = r;
                    g = fs(D(i + 1), p);
                    r = fa(fm(fs(D(i), g), s_), fm(fm(2.0f, c_), b));
                    p = fm(s_, r);
                    D(i + 1) = fa(g, p);
                    g = fs(fm(c_, r), b);
                    WC(i) = c_; WSN(i) = -s_;
                }
                for (int i = mq - 1; i >= l; --i) rotcf(wk, i, i + 1, WC(i), WSN(i));
                D(l) = fs(D(l), p); E(l) = g;
            }
        } else {
            for (;;) {
                int mq = lend;
                if (l != lend) {
                    for (mq = l; mq >= lend + 1; --mq) {
                        float tst = fm(E(mq - 1), E(mq - 1));
                        if (tst <= fa(fm(fm(eps2, fabsf(D(mq))), fabsf(D(mq - 1))), safmin)) break;
                    }
                }
                if (mq > lend) E(mq - 1) = 0.0f;
                float p = D(l);
                if (mq == l) { l -= 1; if (l >= lend) continue; break; }
                if (mq == l - 1) {
                    float rt1, rt2, cc, ss;
                    slaev2_(D(l - 1), E(l - 1), D(l), rt1, rt2, cc, ss);
                    rotcf(wk, l - 1, l, cc, ss);
                    D(l - 1) = rt1; D(l) = rt2; E(l - 1) = 0.0f;
                    l -= 2; if (l >= lend) continue; break;
                }
                if (jtot == nmaxit) break;
                jtot++;
                float g = fs(D(l - 1), p) / fm(2.0f, E(l - 1));
                float r = slapy2_(g, 1.0f);
                g = fa(fs(D(mq), p), E(l - 1) / fa(g, fsignf(r, g)));
                float s_ = 1.0f, c_ = 1.0f; p = 0.0f;
                for (int i = mq; i <= l - 1; ++i) {
                    float f = fm(s_, E(i)), b = fm(c_, E(i));
                    slartg_(g, f, c_, s_, r);
                    if (i != mq) E(i - 1) = r;
                    g = fs(D(i), p);
                    r = fa(fm(fs(D(i + 1), g), s_), fm(fm(2.0f, c_), b));
                    p = fm(s_, r);
                    D(i) = fa(g, p);
                    g = fs(fm(c_, r), b);
                    WC(i) = c_; WSN(i) = s_;
                }
                for (int i = mq; i <= l - 1; ++i) rotcf(wk, i, i + 1, WC(i), WSN(i));
                D(l) = fs(D(l), p); E(l - 1) = g;
            }
        }
    }
    for (int ii = 2; ii <= 3; ++ii) {
        int i = ii - 1, kk = i; float p = D(i);
        for (int j = ii; j <= 3; ++j) if (D(j) < p) { kk = j; p = D(j); }
        if (kk != i) {
            D(kk) = D(i); D(i) = p;
            for (int r = 1; r <= 3; ++r) { float t = Z(r, i); Z(r, i) = Z(r, kk); Z(r, kk) = t; }
        }
    }
    if (tau != 0.0f) {
        for (int c = 1; c <= 3; ++c) {
            float ss = fa(Z(2, c), fm(v3, Z(3, c)));
            float t = fm(tau, ss);
            Z(2, c) = fs(Z(2, c), t);
            Z(3, c) = fs(Z(3, c), fm(t, v3));
        }
    }
    v1o = Z(1, 1); v2o = Z(2, 1); v3o = Z(3, 1);
}

__device__ void threefry2x32_(unsigned k0, unsigned k1, unsigned c0, unsigned c1,
                              unsigned& o0, unsigned& o1) {
    const unsigned rot[8] = {13u, 15u, 26u, 6u, 17u, 29u, 16u, 24u};
    unsigned ks[3] = {k0, k1, k0 ^ k1 ^ 0x1BD11BDAu};
    unsigned x0 = c0 + k0, x1 = c1 + k1;
    for (int blk = 0; blk < 5; ++blk) {
        const unsigned* r = &rot[(blk & 1) * 4];
        for (int i = 0; i < 4; ++i) {
            x0 += x1;
            x1 = (x1 << r[i]) | (x1 >> (32 - r[i]));
            x1 ^= x0;
        }
        x0 += ks[(blk + 1) % 3];
        x1 += ks[(blk + 2) % 3] + (unsigned)(blk + 1);
    }
    o0 = x0; o1 = x1;
}

__device__ float noise_diag_(int j) {
    unsigned m = (unsigned)(4 * j);
    unsigned o0, o1;
    threefry2x32_(0u, 42u, m, 150u + m, o0, o1);
    unsigned bits = (o0 >> 9) | 0x3f800000u;
    float u = fs(__uint_as_float(bits), 1.0f);
    return fm(fs(u, 0.5f), 1e-8f);
}

__device__ __forceinline__ float angf(float ax, float ay, float az,
                                      float bx, float by, float bz) {
    float cx = ay * bz - az * by;
    float cy = az * bx - ax * bz;
    float cz = ax * by - ay * bx;
    float cn = sqrtf(cx * cx + cy * cy + cz * cz);
    float d  = ax * bx + ay * by + az * bz;
    return atan2f(cn, d);
}

__device__ __forceinline__ int cellof(float x, float y, float z) {
    int cx = (int)(x * 16.0f); cx = (cx > 15) ? 15 : cx;
    int cy = (int)(y * 16.0f); cy = (cy > 15) ? 15 : cy;
    int cz = (int)(z * 16.0f); cz = (cz > 15) ? 15 : cz;
    return cx * 256 + cy * 16 + cz;
}

// ---------------------------------------------------------------- grid build

__global__ void k_zero(int* __restrict__ cellCnt) {
    int t = blockIdx.x * blockDim.x + threadIdx.x;
    if (t < NCELLS) cellCnt[t] = 0;
}

__global__ void k_prep(const float* __restrict__ pts, float4* __restrict__ pos4,
                       int* __restrict__ cellCnt, int n) {
    int i = blockIdx.x * blockDim.x + threadIdx.x;
    if (i < n) {
        float x = pts[i * 3], y = pts[i * 3 + 1], z = pts[i * 3 + 2];
        float sq = fa(fa(fm(x, x), fm(y, y)), fm(z, z));
        pos4[i] = make_float4(x, y, z, sq);
        atomicAdd(&cellCnt[cellof(x, y, z)], 1);
    }
}

__global__ __launch_bounds__(256) void k_scan(const int* __restrict__ cellCnt,
                                              int* __restrict__ cellStart,
                                              int* __restrict__ cellCur, int n) {
    __shared__ int part[256];
    int t = threadIdx.x;
    int s = 0;
    for (int z = 0; z < 16; ++z) s += cellCnt[t * 16 + z];
    part[t] = s;
    __syncthreads();
    for (int off = 1; off < 256; off <<= 1) {
        int v = (t >= off) ? part[t - off] : 0;
        __syncthreads();
        part[t] += v;
        __syncthreads();
    }
    int run = part[t] - s;
    for (int z = 0; z < 16; ++z) {
        int idx = t * 16 + z;
        cellStart[idx] = run;
        cellCur[idx] = run;
        run += cellCnt[idx];
    }
    if (t == 255) cellStart[NCELLS] = n;
}

__global__ void k_scatter(const float4* __restrict__ pos4, int* __restrict__ cellCur,
                          float4* __restrict__ spos4, int* __restrict__ sidx, int n) {
    int i = blockIdx.x * blockDim.x + threadIdx.x;
    if (i < n) {
        float4 p = pos4[i];
        int c = cellof(p.x, p.y, p.z);
        int pos = atomicAdd(&cellCur[c], 1);
        spos4[pos] = p;
        sidx[pos] = i;
    }
}

// ---------------------------------------------------------------- KNN (grid)
#define KEY_WORST 0xC0001FFFFFFFFFFFull
#define CAND 512

__device__ __forceinline__ void final_pops(unsigned long long* row, int cnt, int lane,
                                           double& mykey, unsigned long long& twelfth) {
    double k0 = __longlong_as_double((long long)KEY_WORST);
    if (lane < cnt) k0 = __longlong_as_double((long long)row[lane]);
    mykey = __longlong_as_double((long long)KEY_WORST);
    double last = mykey;
    for (int r = 0; r < KNB; ++r) {
        double mx = k0;
#pragma unroll
        for (int off = 32; off >= 1; off >>= 1)
            mx = fmax(mx, __shfl_xor(mx, off, 64));
        if (k0 == mx) k0 = __longlong_as_double((long long)KEY_WORST);
        if (lane == r) mykey = mx;
        last = mx;
    }
    twelfth = (unsigned long long)__double_as_longlong(last);
}

__global__ __launch_bounds__(256) void k_knn(const float4* __restrict__ pos4,
                                             const float4* __restrict__ spos4,
                                             const int* __restrict__ sidx,
                                             const int* __restrict__ cellStart,
                                             int* __restrict__ cols, int n) {
    __shared__ int scand[4][CAND];
    __shared__ unsigned long long scb[4][64];

    int lane = threadIdx.x & 63;
    int wv = threadIdx.x >> 6;
    int i = blockIdx.x * 4 + wv;
    if (i >= n) return;
    float4 P = pos4[i];

    int cix = (int)(P.x * 16.0f); cix = (cix > 15) ? 15 : cix;
    int ciy = (int)(P.y * 16.0f); ciy = (ciy > 15) ? 15 : ciy;
    int ciz = (int)(P.z * 16.0f); ciz = (ciz > 15) ? 15 : ciz;
    int zlo = (ciz - 2 > 0) ? (ciz - 2) : 0;
    int zhi = (ciz + 2 < 15) ? (ciz + 2) : 15;

    int len = 0, st = 0;
    if (lane < 25) {
        int dx = lane / 5 - 2, dy = lane % 5 - 2;
        int cx = cix + dx, cy = ciy + dy;
        if (cx >= 0 && cx <= 15 && cy >= 0 && cy <= 15) {
            int base = cx * 256 + cy * 16;
            st = cellStart[base + zlo];
            len = cellStart[base + zhi + 1] - st;
        }
    }
    int inc = len;
#pragma unroll
    for (int off = 1; off <= 16; off <<= 1) {
        int o = __shfl_up(inc, off, 64);
        if (lane >= off) inc += o;
    }
    int pref = inc - len;
    int total = __shfl(inc, 24, 64);
    bool ovf = (total > CAND);

    if (!ovf && lane < 25) {
        for (int e = 0; e < len; ++e) scand[wv][pref + e] = st + e;
    }
    __builtin_amdgcn_wave_barrier();

    const float cw = 1.0f / 16.0f;
    int lx = (cix - 2 > 0) ? (cix - 2) : 0, hx = (cix + 2 < 15) ? (cix + 2) : 15;
    int ly = (ciy - 2 > 0) ? (ciy - 2) : 0, hy = (ciy + 2 < 15) ? (ciy + 2) : 15;
    float g1 = (lx == 0)  ? 1e9f : (P.x - lx * cw);
    float g2 = (hx == 15) ? 1e9f : ((hx + 1) * cw - P.x);
    float g3 = (ly == 0)  ? 1e9f : (P.y - ly * cw);
    float g4 = (hy == 15) ? 1e9f : ((hy + 1) * cw - P.y);
    float g5 = (zlo == 0) ? 1e9f : (P.z - zlo * cw);
    float g6 = (zhi == 15)? 1e9f : ((zhi + 1) * cw - P.z);
    float guard = fminf(fminf(fminf(g1, g2), fminf(g3, g4)), fminf(g5, g6));
    float guard2 = guard * guard;

    unsigned b0 = 0xFFFFFFFFu, b1 = 0xFFFFFFFFu;
    if (!ovf) {
        for (int t = lane; t < total; t += 64) {
            int s = scand[wv][t];
            float4 Q = spos4[s];
            int j = sidx[s];
            float g = fm(P.x, Q.x);
            g = fmaf(P.y, Q.y, g);
            g = fmaf(P.z, Q.z, g);
            float d2 = fs(fa(P.w, Q.w), fm(2.0f, g));
            unsigned u = __float_as_uint(d2);
            if (j == i) u = 0xFFFFFFFFu;
            unsigned lo = umin32(b0, u);
            unsigned hi = umax32(b0, u);
            b0 = lo;
            b1 = umin32(b1, hi);
        }
    }

    unsigned T = 0xFFFFFFFFu;
    for (int r = 0; r < KNB; ++r) {
        unsigned mn = b0;
#pragma unroll
        for (int off = 32; off >= 1; off >>= 1) {
            unsigned o = (unsigned)__shfl_xor((int)mn, off, 64);
            mn = umin32(mn, o);
        }
        unsigned long long bl = __ballot(b0 == mn);
        int first = __ffsll(bl) - 1;
        if (lane == first) { b0 = b1; b1 = 0xFFFFFFFFu; }
        T = mn;
    }

    int cnt = 0;
    if (!ovf) {
        for (int t = lane; t < total; t += 64) {
            int s = scand[wv][t];
            float4 Q = spos4[s];
            int j = sidx[s];
            float g = fm(P.x, Q.x);
            g = fmaf(P.y, Q.y, g);
            g = fmaf(P.z, Q.z, g);
            float d2 = fs(fa(P.w, Q.w), fm(2.0f, g));
            unsigned u = __float_as_uint(d2);
            bool c = (u <= T) && (j != i);
            unsigned long long bl = __ballot(c);
            if (c) {
                int pos = cnt + (int)__popcll(bl & ((1ull << lane) - 1ull));
                unsigned us = u ^ (unsigned)(((int)u >> 31) | 0x80000000);
                unsigned long long kb = (((unsigned long long)us << 13) | (unsigned)j)
                                        | 0xC000000000000000ull;
                if (pos < 64) scb[wv][pos] = kb;
            }
            cnt += (int)__popcll(bl);
        }
    }

    bool fb = ovf || (cnt > 64) || (total < KNB + 1);
    double mykey; unsigned long long twelfth;
    if (!fb) {
        final_pops(scb[wv], cnt, lane, mykey, twelfth);
        unsigned u12 = (unsigned)((twelfth >> 13) & 0xFFFFFFFFull);
        unsigned ob12 = (u12 & 0x80000000u) ? (u12 ^ 0x80000000u) : ~u12;
        float d2_12 = __uint_as_float(ob12);
        if (!(d2_12 < guard2)) fb = true;
    }

    if (fb) {
        unsigned lst[KNB];
#pragma unroll
        for (int k = 0; k < KNB; ++k) lst[k] = 0xFFFFFFFFu;
        for (int j = lane; j < n; j += 64) {
            float4 Q = pos4[j];
            float g = fm(P.x, Q.x);
            g = fmaf(P.y, Q.y, g);
            g = fmaf(P.z, Q.z, g);
            float d2 = fs(fa(P.w, Q.w), fm(2.0f, g));
            unsigned u = __float_as_uint(d2);
            unsigned us = u ^ (unsigned)(((int)u >> 31) | 0x80000000);
            if (j == i) us = 0xFFFFFFFFu;
#pragma unroll
            for (int k = 0; k < KNB; ++k) {
                unsigned lo = umin32(lst[k], us);
                unsigned hi = umax32(lst[k], us);
                lst[k] = lo; us = hi;
            }
        }
        unsigned Ts = 0xFFFFFFFFu;
        for (int r = 0; r < KNB; ++r) {
            unsigned mn = lst[0];
#pragma unroll
            for (int off = 32; off >= 1; off >>= 1) {
                unsigned o = (unsigned)__shfl_xor((int)mn, off, 64);
                mn = umin32(mn, o);
            }
            unsigned long long bl = __ballot(lst[0] == mn);
            int first = __ffsll(bl) - 1;
            if (lane == first) {
#pragma unroll
                for (int k = 0; k < KNB - 1; ++k) lst[k] = lst[k + 1];
                lst[KNB - 1] = 0xFFFFFFFFu;
            }
            Ts = mn;
        }
        cnt = 0;
        for (int j = lane; j < n; j += 64) {
            float4 Q = pos4[j];
            float g = fm(P.x, Q.x);
            g = fmaf(P.y, Q.y, g);
            g = fmaf(P.z, Q.z, g);
            float d2 = fs(fa(P.w, Q.w), fm(2.0f, g));
            unsigned u = __float_as_uint(d2);
            unsigned us = u ^ (unsigned)(((int)u >> 31) | 0x80000000);
            bool c = (us <= Ts) && (j != i);
            unsigned long long bl = __ballot(c);
            if (c) {
                int pos = cnt + (int)__popcll(bl & ((1ull << lane) - 1ull));
                unsigned long long kb = (((unsigned long long)us << 13) | (unsigned)j)
                                        | 0xC000000000000000ull;
                if (pos < 64) scb[wv][pos] = kb;
            }
            cnt += (int)__popcll(bl);
        }
        if (cnt > 64) cnt = 64;
        final_pops(scb[wv], cnt, lane, mykey, twelfth);
    }

    if (lane < KNB) {
        unsigned long long bits = (unsigned long long)__double_as_longlong(mykey);
        unsigned j = (unsigned)(bits & 0x1FFFu);
        unsigned u = (unsigned)((bits >> 13) & 0xFFFFFFFFull);
        unsigned ob = (u & 0x80000000u) ? (u ^ 0x80000000u) : ~u;
        float d2 = __uint_as_float(ob);
        cols[i * KNB + lane] = (d2 <= 0.25f) ? (int)j : i;
    }
}

// ---------------------------------------------------------------- normals
__global__ __launch_bounds__(64) void k_normals(const float4* __restrict__ pos4,
                                                const int* __restrict__ cols,
                                                float4* __restrict__ nrm4,
                                                float* __restrict__ out, int n) {
    __shared__ float swk[64][19];
    int i = blockIdx.x * blockDim.x + threadIdx.x;
    if (i >= n) return;
    float* wk = swk[threadIdx.x];

    float qx[KNB], qy[KNB], qz[KNB];
#pragma unroll
    for (int k = 0; k < KNB; ++k) {
        float4 q = pos4[cols[i * KNB + k]];
        qx[k] = q.x; qy[k] = q.y; qz[k] = q.z;
    }
    float sx = qx[0], sy = qy[0], sz = qz[0];
#pragma unroll
    for (int k = 1; k < KNB; ++k) { sx = fa(sx, qx[k]); sy = fa(sy, qy[k]); sz = fa(sz, qz[k]); }
    float mx = sx / 12.0f, my = sy / 12.0f, mz = sz / 12.0f;
    float c00 = 0, c10 = 0, c20 = 0, c11 = 0, c21 = 0, c22 = 0;
#pragma unroll
    for (int k = 0; k < KNB; ++k) {
        float dx = fs(qx[k], mx), dy = fs(qy[k], my), dz = fs(qz[k], mz);
        c00 = fa(c00, fm(dx, dx));
        c10 = fa(c10, fm(dy, dx));
        c20 = fa(c20, fm(dz, dx));
        c11 = fa(c11, fm(dy, dy));
        c21 = fa(c21, fm(dz, dy));
        c22 = fa(c22, fm(dz, dz));
    }
    c00 = c00 / 12.0f; c10 = c10 / 12.0f; c20 = c20 / 12.0f;
    c11 = c11 / 12.0f; c21 = c21 / 12.0f; c22 = c22 / 12.0f;
    float v0 = noise_diag_(0), v1 = noise_diag_(1), v2 = noise_diag_(2);
    float a00 = fa(c00, v0), a10 = fa(c10, v0), a20 = fa(c20, v0);
    float a11 = fa(c11, v1), a21 = fa(c21, v1), a22 = fa(c22, v2);
    float e1, e2, e3;
    eig3_smallest_f32(wk, a00, a10, a20, a11, a21, a22, e1, e2, e3);
    nrm4[i] = make_float4(e1, e2, e3, 0.0f);
    out[i]         = e1;
    out[n + i]     = e2;
    out[2 * n + i] = e3;
}

// ---------------------------------------------------------------- MLP chain
// Thread-per-edge (wave-uniform weight addresses) with weights staged in LDS
// in TRANSPOSED, padded layouts: w1T[h][ii] (ii consecutive -> ds_read_b128
// merge), w2[h][o] (o consecutive). All weight reads are broadcast ds_reads
// on the DS pipe (no SMEM drain stalls, no per-lane VMEM). sx stride 17
// kills R12's 1M bank conflicts.

struct WPtrs { const float* p[28]; };

// LDS weight arena offsets (floats)
enum {
    oL1W = 0,            // 32 x 8   (NI=7, NIP=8)
    oL1B = 256,          // 32
    oL1V = 288,          // 32 x 16
    oL1C = 800,          // 16
    oG1W = 816,          // 32 x 20  (NI=19, NIP=20)
    oG1B = 1456,         // 32
    oG1V = 1488,         // 32 x 8
    oG1C = 1744,         // 8
    oL2W = 1752,         // 32 x 24
    oL2B = 2520,         // 32
    oL2V = 2552,         // 32 x 16
    oL2C = 3064,         // 16
    oG2W = 3080,         // 32 x 16
    oG2B = 3592,         // 32
    oG2V = 3624,         // 32 x 8
    oG2C = 3880,         // 8
    oL3W = 3888,         // 32 x 24
    oL3B = 4656,         // 32
    oL3V = 4688,         // 32 x 16
    oL3C = 5200,         // 16
    oG3W = 5216,         // 32 x 16
    oG3B = 5728,         // 32
    oG3V = 5760,         // 32 x 12
    oG3C = 6144,         // 12
    oL4W = 6156,         // 64 x 28  (NI=27, NIP=28)
    oL4B = 7948,         // 64
    oL4V = 8012,         // 64 x 1
    oL4C = 8076,         // 1
    WARENA = 8077
};

// mlp from LDS: w1T[h*NIP+ii], b1[h], w2[h*NO+o], b2[o]
template <int NI, int NIP, int NH, int NO>
__device__ void mlps(const float* __restrict__ sw, int w1o, int b1o, int w2o, int b2o,
                     const float* in, float* out) {
#pragma unroll
    for (int o = 0; o < NO; ++o) out[o] = sw[b2o + o];
#pragma unroll 4
    for (int h = 0; h < NH; ++h) {
        float hh = sw[b1o + h];
#pragma unroll
        for (int ii = 0; ii < NI; ++ii) hh = fmaf(in[ii], sw[w1o + h * NIP + ii], hh);
        hh = fmaxf(hh, 0.0f);
#pragma unroll
        for (int o = 0; o < NO; ++o) out[o] = fmaf(hh, sw[w2o + h * NO + o], out[o]);
    }
}

__global__ __launch_bounds__(192) void k_mlp(const float4* __restrict__ pos4,
                                             const int* __restrict__ cols,
                                             const float4* __restrict__ nrm4,
                                             WPtrs wp, float* __restrict__ out, int n) {
    __shared__ float sw[WARENA];
    __shared__ float sx[16 * 12 * 17];   // stride 17: conflict-free
    __shared__ float sg[16 * 12];
    __shared__ float smat[16 * 9];
    __shared__ float sfeat[16 * 8];
    __shared__ float slog[16 * 12];
    __shared__ float sred[16 * 2];

    int tid = threadIdx.x;

    // ---- stage weights (transposed w1: dst[h*NIP+ii] = src[ii*NH+h])
    {
        // l1 (7,8,32,16)
        for (int e = tid; e < 7 * 32; e += 192) { int ii = e / 32, h = e % 32; sw[oL1W + h * 8 + ii] = wp.p[0][e]; }
        for (int e = tid; e < 32; e += 192) sw[oL1B + e] = wp.p[1][e];
        for (int e = tid; e < 512; e += 192) sw[oL1V + e] = wp.p[2][e];
        for (int e = tid; e < 16; e += 192) sw[oL1C + e] = wp.p[3][e];
        // g1 (19,20,32,8)
        for (int e = tid; e < 19 * 32; e += 192) { int ii = e / 32, h = e % 32; sw[oG1W + h * 20 + ii] = wp.p[4][e]; }
        for (int e = tid; e < 32; e += 192) sw[oG1B + e] = wp.p[5][e];
        for (int e = tid; e < 256; e += 192) sw[oG1V + e] = wp.p[6][e];
        for (int e = tid; e < 8; e += 192) sw[oG1C + e] = wp.p[7][e];
        // l2 (24,24,32,16)
        for (int e = tid; e < 24 * 32; e += 192) { int ii = e / 32, h = e % 32; sw[oL2W + h * 24 + ii] = wp.p[8][e]; }
        for (int e = tid; e < 32; e += 192) sw[oL2B + e] = wp.p[9][e];
        for (int e = tid; e < 512; e += 192) sw[oL2V + e] = wp.p[10][e];
        for (int e = tid; e < 16; e += 192) sw[oL2C + e] = wp.p[11][e];
        // g2 (16,16,32,8)
        for (int e = tid; e < 16 * 32; e += 192) { int ii = e / 32, h = e % 32; sw[oG2W + h * 16 + ii] = wp.p[12][e]; }
        for (int e = tid; e < 32; e += 192) sw[oG2B + e] = wp.p[13][e];
        for (int e = tid; e < 256; e += 192) sw[oG2V + e] = wp.p[14][e];
        for (int e = tid; e < 8; e += 192) sw[oG2C + e] = wp.p[15][e];
        // l3 (24,24,32,16)
        for (int e = tid; e < 24 * 32; e += 192) { int ii = e / 32, h = e % 32; sw[oL3W + h * 24 + ii] = wp.p[16][e]; }
        for (int e = tid; e < 32; e += 192) sw[oL3B + e] = wp.p[17][e];
        for (int e = tid; e < 512; e += 192) sw[oL3V + e] = wp.p[18][e];
        for (int e = tid; e < 16; e += 192) sw[oL3C + e] = wp.p[19][e];
        // g3 (16,16,32,12)
        for (int e = tid; e < 16 * 32; e += 192) { int ii = e / 32, h = e % 32; sw[oG3W + h * 16 + ii] = wp.p[20][e]; }
        for (int e = tid; e < 32; e += 192) sw[oG3B + e] = wp.p[21][e];
        for (int e = tid; e < 384; e += 192) sw[oG3V + e] = wp.p[22][e];
        for (int e = tid; e < 12; e += 192) sw[oG3C + e] = wp.p[23][e];
        // l4 (27,28,64,1)
        for (int e = tid; e < 27 * 64; e += 192) { int ii = e / 64, h = e % 64; sw[oL4W + h * 28 + ii] = wp.p[24][e]; }
        for (int e = tid; e < 64; e += 192) sw[oL4B + e] = wp.p[25][e];
        for (int e = tid; e < 64; e += 192) sw[oL4V + e] = wp.p[26][e];
        if (tid == 0) sw[oL4C] = wp.p[27][0];
    }
    __syncthreads();

    int p = tid / 12, k = tid - p * 12;
    int nn = blockIdx.x * 16 + p;
    bool act = (nn < n);

    float cx = 0, cy = 0, cz = 0, nrx = 0, nry = 0, nrz = 0;
    float xr[16];

    // stage A: edge features + l1
    if (act) {
        int col = cols[nn * 12 + k];
        float4 P = pos4[nn], Q = pos4[col];
        cx = Q.x - P.x; cy = Q.y - P.y; cz = Q.z - P.z;
        float dist = sqrtf(cx * cx + cy * cy + cz * cz);
        float4 NR = nrm4[nn], NC = nrm4[col];
        nrx = NR.x; nry = NR.y; nrz = NR.z;
        float a1 = angf(nrx, nry, nrz, cx, cy, cz);
        float a2 = angf(NC.x, NC.y, NC.z, cx, cy, cz);
        float a3 = angf(nrx, nry, nrz, NC.x, NC.y, NC.z);
        float in7[7] = {cx, cy, cz, dist, a1, a2, a3};
        mlps<7, 8, 32, 16>(sw, oL1W, oL1B, oL1V, oL1C, in7, xr);
#pragma unroll
        for (int o = 0; o < 16; ++o) sx[(p * 12 + k) * 17 + o] = xr[o];
    }
    __syncthreads();

    // stage B: g1
    if (act && k == 0) {
        float in19[19];
#pragma unroll
        for (int o = 0; o < 16; ++o) {
            float s = 0;
            for (int kk = 0; kk < 12; ++kk) s += sx[(p * 12 + kk) * 17 + o];
            in19[o] = s / 12.0f;
        }
        in19[16] = nrx; in19[17] = nry; in19[18] = nrz;
        float og[8];
        mlps<19, 20, 32, 8>(sw, oG1W, oG1B, oG1V, oG1C, in19, og);
#pragma unroll
        for (int o = 0; o < 8; ++o) sg[p * 12 + o] = og[o];
    }
    __syncthreads();

    // stage C: l2
    if (act) {
        float in24[24];
#pragma unroll
        for (int o = 0; o < 16; ++o) in24[o] = xr[o];
#pragma unroll
        for (int o = 0; o < 8; ++o) in24[16 + o] = sg[p * 12 + o];
        mlps<24, 24, 32, 16>(sw, oL2W, oL2B, oL2V, oL2C, in24, xr);
#pragma unroll
        for (int o = 0; o < 16; ++o) sx[(p * 12 + k) * 17 + o] = xr[o];
    }
    __syncthreads();

    // stage D: g2
    if (act && k == 0) {
        float in16[16];
#pragma unroll
        for (int o = 0; o < 16; ++o) {
            float s = 0;
            for (int kk = 0; kk < 12; ++kk) s += sx[(p * 12 + kk) * 17 + o];
            in16[o] = s / 12.0f;
        }
        float og[8];
        mlps<16, 16, 32, 8>(sw, oG2W, oG2B, oG2V, oG2C, in16, og);
#pragma unroll
        for (int o = 0; o < 8; ++o) sg[p * 12 + o] = og[o];
    }
    __syncthreads();

    // stage E: l3
    if (act) {
        float in24[24];
#pragma unroll
        for (int o = 0; o < 16; ++o) in24[o] = xr[o];
#pragma unroll
        for (int o = 0; o < 8; ++o) in24[16 + o] = sg[p * 12 + o];
        mlps<24, 24, 32, 16>(sw, oL3W, oL3B, oL3V, oL3C, in24, xr);
#pragma unroll
        for (int o = 0; o < 16; ++o) sx[(p * 12 + k) * 17 + o] = xr[o];
    }
    __syncthreads();

    // stage F: g3 + quat -> rot matrix
    if (act && k == 0) {
        float in16[16];
#pragma unroll
        for (int o = 0; o < 16; ++o) {
            float s = 0;
            for (int kk = 0; kk < 12; ++kk) s += sx[(p * 12 + kk) * 17 + o];
            in16[o] = s / 12.0f;
        }
        float og[12];
        mlps<16, 16, 32, 12>(sw, oG3W, oG3B, oG3V, oG3C, in16, og);
        float q0 = og[0], q1 = og[1], q2 = og[2], q3 = og[3];
        float qn = sqrtf(q0 * q0 + q1 * q1 + q2 * q2 + q3 * q3) + 1e-8f;
        q0 /= qn; q1 /= qn; q2 /= qn; q3 /= qn;
        float qw = q0, qx = q1, qy = q2, qz = q3;
        smat[p * 9 + 0] = 1.0f - 2.0f * (qy * qy + qz * qz);
        smat[p * 9 + 1] = 2.0f * (qx * qy - qz * qw);
        smat[p * 9 + 2] = 2.0f * (qx * qz + qy * qw);
        smat[p * 9 + 3] = 2.0f * (qx * qy + qz * qw);
        smat[p * 9 + 4] = 1.0f - 2.0f * (qx * qx + qz * qz);
        smat[p * 9 + 5] = 2.0f * (qy * qz - qx * qw);
        smat[p * 9 + 6] = 2.0f * (qx * qz - qy * qw);
        smat[p * 9 + 7] = 2.0f * (qy * qz + qx * qw);
        smat[p * 9 + 8] = 1.0f - 2.0f * (qx * qx + qy * qy);
#pragma unroll
        for (int o = 0; o < 8; ++o) sfeat[p * 8 + o] = og[4 + o];
    }
    __syncthreads();

    // stage G: l4 logits
    if (act) {
        float r0 = smat[p * 9 + 0] * cx + smat[p * 9 + 1] * cy + smat[p * 9 + 2] * cz;
        float r1 = smat[p * 9 + 3] * cx + smat[p * 9 + 4] * cy + smat[p * 9 + 5] * cz;
        float r2 = smat[p * 9 + 6] * cx + smat[p * 9 + 7] * cy + smat[p * 9 + 8] * cz;
        float in27[27];
#pragma unroll
        for (int o = 0; o < 16; ++o) in27[o] = xr[o];
#pragma unroll
        for (int o = 0; o < 8; ++o) in27[16 + o] = sfeat[p * 8 + o];
        in27[24] = r0; in27[25] = r1; in27[26] = r2;
        float lg[1];
        mlps<27, 28, 64, 1>(sw, oL4W, oL4B, oL4V, oL4C, in27, lg);
        slog[p * 12 + k] = lg[0];
    }
    __syncthreads();

    // stage H: softmax over the 12 edges
    if (act && k == 0) {
        float mx = slog[p * 12];
        for (int kk = 1; kk < 12; ++kk) mx = fmaxf(mx, slog[p * 12 + kk]);
        float se = 0;
        for (int kk = 0; kk < 12; ++kk) se += expf(slog[p * 12 + kk] - mx);
        sred[p * 2] = mx; sred[p * 2 + 1] = se;
    }
    __syncthreads();
    if (act) {
        float v = expf(slog[p * 12 + k] - sred[p * 2]) / sred[p * 2 + 1];
        out[3 * n + k * n + nn] = v;
    }
}

// ---------------------------------------------------------------- launch

extern "C" void kernel_launch(void* const* d_in, const int* in_sizes, int n_in,
                              void* d_out, int out_size, void* d_ws, size_t ws_size,
                              hipStream_t stream) {
    const float* pts = (const float*)d_in[0];
    int n = in_sizes[0] / 3;

    char* w = (char*)d_ws;
    float4* pos4      = (float4*)w;                    w += (size_t)n * 16;
    int*    cols      = (int*)w;                       w += (size_t)n * KNB * 4;
    float4* nrm4      = (float4*)w;                    w += (size_t)n * 16;
    float4* spos4     = (float4*)w;                    w += (size_t)n * 16;
    int*    sidx      = (int*)w;                       w += (size_t)n * 4;
    int*    cellCnt   = (int*)w;                       w += (size_t)NCELLS * 4;
    int*    cellStart = (int*)w;                       w += (size_t)(NCELLS + 1) * 4;
    int*    cellCur   = (int*)w;
    float*  out       = (float*)d_out;

    WPtrs wp;
    for (int a = 0; a < 28; ++a) wp.p[a] = (const float*)d_in[a + 1];

    k_zero<<<(NCELLS + 255) / 256, 256, 0, stream>>>(cellCnt);
    k_prep<<<(n + 255) / 256, 256, 0, stream>>>(pts, pos4, cellCnt, n);
    k_scan<<<1, 256, 0, stream>>>(cellCnt, cellStart, cellCur, n);
    k_scatter<<<(n + 255) / 256, 256, 0, stream>>>(pos4, cellCur, spos4, sidx, n);
    k_knn<<<(n + 3) / 4, 256, 0, stream>>>(pos4, spos4, sidx, cellStart, cols, n);
    k_normals<<<(n + 63) / 64, 64, 0, stream>>>(pos4, cols, nrm4, out, n);
    k_mlp<<<(n + 15) / 16, 192, 0, stream>>>(pos4, cols, nrm4, wp, out, n);
}